// Round 11
// baseline (620.630 us; speedup 1.0000x reference)
//
#include <hip/hip_runtime.h>
#include <hip/hip_bf16.h>
#include <hip/hip_cooperative_groups.h>

#define OUT1 16777216    // 4*64*256*256
#define BIG  33554432    // 4*128*256*256

namespace cg = cooperative_groups;

typedef _Float16 half8 __attribute__((ext_vector_type(8)));
typedef float    floatx4 __attribute__((ext_vector_type(4)));

struct __align__(8) h4s { _Float16 x, y, z, w; };
struct __align__(16) au16 { h4s a, u; };         // 4 px of (a, u) interleaved, one 16-B unit

// ---------------- K0: fold weights (f16): Wch(384x64), Wof(64x128), bct --------------------
__global__ __launch_bounds__(256) void k_comb(const float* __restrict__ W_in, const float* __restrict__ b_in,
        const float* __restrict__ W_delta, const float* __restrict__ b_delta,
        const float* __restrict__ W_B, const float* __restrict__ b_B,
        const float* __restrict__ A_param, const float* __restrict__ W_out,
        _Float16* __restrict__ Wch, _Float16* __restrict__ Wof, float* __restrict__ bct){
    int i = blockIdx.x*256 + threadIdx.x;
    if (i < 24576){
        int r = i >> 6, c = i & 63;
        float v;
        if (r < 128) v = W_in[i];
        else if (r < 256){
            int rr = r-128; float s = 0.f;
            for (int k=0;k<128;k++) s = fmaf(W_delta[(rr<<7)+k], W_in[(k<<6)+c], s);
            v = s;
        } else {
            int rr = r-256; float s = 0.f;
            for (int k=0;k<128;k++) s = fmaf(W_B[(rr<<7)+k], W_in[(k<<6)+c], s);
            v = s;
        }
        Wch[i] = (_Float16)v;
    } else if (i < 32768){
        Wof[i-24576] = (_Float16)W_out[i-24576];   // [o][k] row-major, 64x128
    } else if (i < 33280){
        // interleaved per-channel epilogue table: bct[c] = (bI, bD, bB, -exp(A))  [float4]
        int j = i - 32768;                         // 0..511
        int c = j >> 2, comp = j & 3;
        float v;
        if (comp == 0) v = b_in[c];
        else if (comp == 1){
            float s = b_delta[c];
            for (int k=0;k<128;k++) s = fmaf(W_delta[(c<<7)+k], b_in[k], s);
            v = s;
        } else if (comp == 2){
            float s = b_B[c];
            for (int k=0;k<128;k++) s = fmaf(W_B[(c<<7)+k], b_in[k], s);
            v = s;
        } else {
            v = -expf(A_param[c]);
        }
        bct[j] = v;
    }
}

// ---------------- MEGA: proj -> scan -> out in one cooperative kernel ------------------------
// 256 blocks x 1024 threads = 1 block/CU (co-resident; ~110 VGPR < 128 cap, LDS 48 KB union).
// Phase P: round-10 k_proj re-tiled (2 spans/block, 16 waves x 16 px, 2 chunks of 256 px).
// Phase S: round-10 k_scan_wh v5b verbatim, 2 planes/block.
// Phase O: round-10 k_out verbatim, 4 old-blocks per block as 256-thread groups.
// grid.sync() + __threadfence() between phases replaces 2 kernel boundaries.
union MegaLds {
    _Float16 Ws[24576];                           // phase P: 48 KB swizzled weights
    struct {
        _Float16 As2[16][256], Us2[16][256];      // 8 + 8 KB
        float    Wsc[16][256];                    // 16 KB
        _Float16 Shs[16][256];                    // 8 KB  (40 KB)
    } s;
};

__global__ __launch_bounds__(1024, 4) void k_mega(const float* __restrict__ x, const float* __restrict__ prior,
        const _Float16* __restrict__ Wch, const float* __restrict__ bct,
        const float* __restrict__ lam_p, const float* __restrict__ alp_p,
        float* __restrict__ pu, au16* __restrict__ AU, _Float16* __restrict__ Sh,
        const _Float16* __restrict__ Wof, const float* __restrict__ bout,
        const float* __restrict__ gam_p, float* __restrict__ out){
    __shared__ MegaLds L;
    cg::grid_group grid = cg::this_grid();

    const int t    = threadIdx.x;                  // 0..1023
    const int lane = t & 63;
    const int w16  = t >> 6;                       // 0..15
    const int col  = lane & 15;
    const int quad = lane >> 4;

    // ================= PHASE P: MFMA projection + inline bilinear prior =================
    {
        // ---- stage Wch (48 KB) into LDS, XOR-swizzled 16B granules (once per block) ----
        const float4* wsrc = (const float4*)Wch;   // 3072 x 16B chunks
        #pragma unroll
        for (int i = 0; i < 3; i++){
            int c = t + (i << 10);                 // 0..3071
            int row = c >> 3, part = c & 7;
            float4 v = wsrc[c];
            int byteoff = ((row << 7) + (part << 4)) ^ ((row & 7) << 4);
            *(float4*)((char*)L.Ws + byteoff) = v;
        }

        const float lamv = lam_p[0], alpv = alp_p[0];
        const int qb = quad << 4;
        const char* wsb = (const char*)L.Ws;
        bool staged_sync = false;

        #pragma unroll 1
        for (int sp = 0; sp < 2; sp++){
            const int bl      = blockIdx.x*2 + sp; // 0..511 (old span id)
            const int b       = bl >> 7;
            const int px_base = (bl & 127) << 9;   // 512-px span
            const float* xcol = x + ((size_t)b<<22) + col;

            // prefetch chunk 0 A-values (f32)
            float xf0[8], xf1[8];
            {
                const float* xp = xcol + px_base + (w16<<4);
                #pragma unroll
                for (int j = 0; j < 8; j++){
                    xf0[j] = xp[(size_t)(quad*8 + j) << 16];
                    xf1[j] = xp[(size_t)(quad*8 + j + 32) << 16];
                }
            }
            if (!staged_sync){ __syncthreads(); staged_sync = true; }  // Ws ready

            #pragma unroll 1
            for (int ch = 0; ch < 2; ch++){
                const int pxw = px_base + (ch << 8) + (w16 << 4);

                half8 aX0, aX1;
                #pragma unroll
                for (int j = 0; j < 8; j++){
                    aX0[j] = (_Float16)xf0[j];
                    aX1[j] = (_Float16)xf1[j];
                }
                if (ch < 1){
                    const float* xn = xcol + pxw + 256;
                    #pragma unroll
                    for (int j = 0; j < 8; j++){
                        xf0[j] = xn[(size_t)(quad*8 + j) << 16];
                        xf1[j] = xn[(size_t)(quad*8 + j + 32) << 16];
                    }
                }

                // inline bilinear prior (bit-identical to round-10)
                const float scale = 63.0f/255.0f;
                int yy = pxw >> 8;
                float sy = yy*scale;
                int y0 = min((int)floorf(sy), 63);
                int y1 = min(y0+1, 63);
                float wy = sy - (float)y0;
                const float* pb0 = prior + (b<<12) + (y0<<6);
                const float* pb1 = prior + (b<<12) + (y1<<6);
                int xx0 = (pxw & 255) + (quad<<2);
                float lpu[4], apu[4];
                float4 puo;
                #pragma unroll
                for (int r = 0; r < 4; r++){
                    float sx = (float)(xx0 + r)*scale;
                    int x0 = min((int)floorf(sx), 63);
                    int x1 = min(x0+1, 63);
                    float wx = sx - (float)x0;
                    float r0 = pb0[x0]*(1.f-wy) + pb1[x0]*wy;
                    float r1 = pb0[x1]*(1.f-wy) + pb1[x1]*wy;
                    float pv = fminf(fmaxf(r0*(1.f-wx) + r1*wx, -1.f), 1.f);
                    ((float*)&puo)[r] = pv;
                    lpu[r] = lamv * pv;
                    apu[r] = fmaf(alpv, pv, 1.f);
                }
                *(float4*)(pu + (b<<16) + pxw + (quad<<2)) = puo;

                #pragma unroll 2
                for (int ct = 0; ct < 8; ct++){
                    int rI = (ct << 4) + col;
                    int xr = (rI & 7) << 4;
                    half8 wI0 = *(const half8*)(wsb + ((( rI       << 7) +      qb) ^ xr));
                    half8 wI1 = *(const half8*)(wsb + ((( rI       << 7) + 64 + qb) ^ xr));
                    half8 wD0 = *(const half8*)(wsb + ((((rI + 128)<< 7) +      qb) ^ xr));
                    half8 wD1 = *(const half8*)(wsb + ((((rI + 128)<< 7) + 64 + qb) ^ xr));
                    half8 wB0 = *(const half8*)(wsb + ((((rI + 256)<< 7) +      qb) ^ xr));
                    half8 wB1 = *(const half8*)(wsb + ((((rI + 256)<< 7) + 64 + qb) ^ xr));

                    floatx4 aI = (floatx4){0.f,0.f,0.f,0.f};
                    floatx4 aD = (floatx4){0.f,0.f,0.f,0.f};
                    floatx4 aB = (floatx4){0.f,0.f,0.f,0.f};
                    aI = __builtin_amdgcn_mfma_f32_16x16x32_f16(aX0, wI0, aI, 0, 0, 0);
                    aD = __builtin_amdgcn_mfma_f32_16x16x32_f16(aX0, wD0, aD, 0, 0, 0);
                    aB = __builtin_amdgcn_mfma_f32_16x16x32_f16(aX0, wB0, aB, 0, 0, 0);
                    aI = __builtin_amdgcn_mfma_f32_16x16x32_f16(aX1, wI1, aI, 0, 0, 0);
                    aD = __builtin_amdgcn_mfma_f32_16x16x32_f16(aX1, wD1, aD, 0, 0, 0);
                    aB = __builtin_amdgcn_mfma_f32_16x16x32_f16(aX1, wB1, aB, 0, 0, 0);

                    int c = (ct<<4) + col;
                    float4 bv = *(const float4*)(bct + (c<<2));
                    au16 ov;
                    #pragma unroll
                    for (int r = 0; r < 4; r++){
                        float sI = aI[r] + bv.x;
                        float sD = aD[r] + bv.y;
                        float sB = aB[r] + bv.z;
                        float dpre  = sD + lpu[r];
                        float delta = fmaxf(dpre, 0.f) + __logf(1.f + __expf(-fabsf(dpre)));
                        float ab    = __expf(bv.w * delta);
                        float uu    = delta * sB * apu[r] * sI;
                        (&ov.a.x)[r] = (_Float16)ab;
                        (&ov.u.x)[r] = (_Float16)uu;
                    }
                    size_t u = (((size_t)((b<<7) + c)) << 14) + (pxw >> 2) + quad;
                    AU[u] = ov;
                }
            }
        }
    }

    __threadfence();
    grid.sync();

    // ================= PHASE S: fused W+H scan (v5b body), 2 planes/block =================
    #pragma unroll 1
    for (int pp = 0; pp < 2; pp++){
        const size_t plane = (size_t)(blockIdx.x*2 + pp);   // b*128 + c
        const size_t bI = plane >> 7, cI = plane & 127;
        float Hcol = 0.f;
        const size_t ub = (plane << 14) + lane;

        au16 cur = AU[ub + ((size_t)w16 << 6)];

        #pragma unroll 1
        for (int g = 0; g < 16; g++){
            au16 nxt = cur;
            if (g < 15) nxt = AU[ub + ((size_t)(((g + 1) << 4) + w16) << 6)];

            {
                float ax=(float)cur.a.x, ay=(float)cur.a.y, az=(float)cur.a.z, aw=(float)cur.a.w;
                float ux=(float)cur.u.x, uy=(float)cur.u.y, uz=(float)cur.u.z, uw=(float)cur.u.w;

                float A = ax, U = ux;
                U = fmaf(ay, U, uy); A *= ay;
                U = fmaf(az, U, uz); A *= az;
                U = fmaf(aw, U, uw); A *= aw;
                #pragma unroll
                for (int off=1; off<64; off<<=1){
                    float Apv = __shfl_up(A, off, 64);
                    float Upv = __shfl_up(U, off, 64);
                    if (lane >= off){ U = fmaf(A, Upv, U); A *= Apv; }
                }
                float h = __shfl_up(U, 1, 64);
                if (lane == 0) h = 0.f;
                float4 o;
                h = fmaf(ax, h, ux); o.x = h;
                h = fmaf(ay, h, uy); o.y = h;
                h = fmaf(az, h, uz); o.z = h;
                h = fmaf(aw, h, uw); o.w = h;

                int c0 = lane << 2;
                *(h4s*)&L.s.As2[w16][c0] = cur.a;
                *(h4s*)&L.s.Us2[w16][c0] = cur.u;
                *(float4*)&L.s.Wsc[w16][c0] = o;
            }

            asm volatile("s_waitcnt lgkmcnt(0)" ::: "memory");
            __builtin_amdgcn_sched_barrier(0);
            __builtin_amdgcn_s_barrier();
            __builtin_amdgcn_sched_barrier(0);

            if (t < 256){
                #pragma unroll
                for (int v = 0; v < 16; v++){
                    Hcol = fmaf((float)L.s.As2[v][t], Hcol, (float)L.s.Us2[v][t]);
                    L.s.Shs[v][t] = (_Float16)(Hcol + L.s.Wsc[v][t]);
                }
            }

            asm volatile("s_waitcnt lgkmcnt(0)" ::: "memory");
            __builtin_amdgcn_sched_barrier(0);
            __builtin_amdgcn_s_barrier();
            __builtin_amdgcn_sched_barrier(0);

            {
                h4s sv = *(h4s*)&L.s.Shs[w16][lane << 2];
                size_t hh = (size_t)((g << 4) + w16);
                *(h4s*)(Sh + (bI<<23) + (hh<<15) + (cI<<8) + (lane<<2)) = sv;
            }

            cur = nxt;
        }
    }

    __threadfence();
    grid.sync();

    // ================= PHASE O: MFMA output conv + residual, 4 old-blocks/block ===========
    {
        const int old_idx = blockIdx.x*4 + (t >> 8);       // 0..1023
        const int b    = old_idx >> 8;
        const int hh   = old_idx & 255;
        const int p0   = hh << 8;
        const int w4   = (t >> 6) & 3;                     // wave within 256-thr group
        const int wn0  = w4 << 6;

        const _Float16* shb = Sh + ((size_t)b<<23) + ((size_t)hh<<15);

        floatx4 acc[4][4];
        #pragma unroll
        for (int mt = 0; mt < 4; mt++)
            #pragma unroll
            for (int nt = 0; nt < 4; nt++)
                acc[mt][nt] = (floatx4){0.f,0.f,0.f,0.f};

        #pragma unroll
        for (int kc = 0; kc < 4; kc++){
            half8 af[4];
            #pragma unroll
            for (int mt = 0; mt < 4; mt++)
                #pragma unroll
                for (int j = 0; j < 8; j++)
                    af[mt][j] = shb[((kc*32 + quad*8 + j)<<8) + wn0 + mt*16 + col];
            half8 bf[4];
            #pragma unroll
            for (int nt = 0; nt < 4; nt++)
                bf[nt] = *(const half8*)(Wof + (nt*16 + col)*128 + kc*32 + quad*8);
            #pragma unroll
            for (int mt = 0; mt < 4; mt++)
                #pragma unroll
                for (int nt = 0; nt < 4; nt++)
                    acc[mt][nt] = __builtin_amdgcn_mfma_f32_16x16x32_f16(af[mt], bf[nt], acc[mt][nt], 0, 0, 0);
        }

        const float gv = gam_p[0];
        #pragma unroll
        for (int nt = 0; nt < 4; nt++){
            int o = nt*16 + col;
            float bo = bout[o];
            #pragma unroll
            for (int mt = 0; mt < 4; mt++){
                size_t idx = (((size_t)(b*64 + o))<<16) + p0 + wn0 + mt*16 + (quad<<2);
                float4 xv = *(const float4*)(x + idx);
                float4 ov;
                ov.x = fmaf(gv, acc[mt][nt][0] + bo, xv.x);
                ov.y = fmaf(gv, acc[mt][nt][1] + bo, xv.y);
                ov.z = fmaf(gv, acc[mt][nt][2] + bo, xv.z);
                ov.w = fmaf(gv, acc[mt][nt][3] + bo, xv.w);
                *(float4*)(out + idx) = ov;
            }
        }
    }
}

extern "C" void kernel_launch(void* const* d_in, const int* in_sizes, int n_in,
                              void* d_out, int out_size, void* d_ws, size_t ws_size,
                              hipStream_t stream){
    const float* x       = (const float*)d_in[0];
    const float* prior   = (const float*)d_in[1];
    const float* W_in    = (const float*)d_in[2];
    const float* b_in    = (const float*)d_in[3];
    const float* W_out   = (const float*)d_in[4];
    const float* b_out   = (const float*)d_in[5];
    const float* W_delta = (const float*)d_in[6];
    const float* b_delta = (const float*)d_in[7];
    const float* W_B     = (const float*)d_in[8];
    const float* b_B     = (const float*)d_in[9];
    const float* A_param = (const float*)d_in[10];
    const float* lam     = (const float*)d_in[11];
    const float* alp     = (const float*)d_in[12];
    const float* gam     = (const float*)d_in[13];

    float* out = (float*)d_out;
    float* pu  = out + OUT1;                   // prior_up = output 1

    float* ws        = (float*)d_ws;
    _Float16* Wch    = (_Float16*)ws;          // 24576 f16 -> float-offset [0,12288)
    _Float16* Wof    = (_Float16*)(ws + 12800);// 8192 f16 -> [12800,16896)
    float* bct       = ws + 16896;             // 512 floats (128 x float4)
    au16* AU         = (au16*)(ws + 32768);    // BIG/4 units x 16 B = 134 MB
    _Float16* Sh     = (_Float16*)(AU + BIG/4);// BIG f16 = 67 MB, layout [b][h][c][w]

    hipLaunchKernelGGL(k_comb, dim3(130), dim3(256), 0, stream, W_in, b_in, W_delta, b_delta,
                       W_B, b_B, A_param, W_out, Wch, Wof, bct);

    void* args[] = { (void*)&x, (void*)&prior, (void*)&Wch, (void*)&bct, (void*)&lam, (void*)&alp,
                     (void*)&pu, (void*)&AU, (void*)&Sh, (void*)&Wof, (void*)&b_out,
                     (void*)&gam, (void*)&out };
    hipLaunchCooperativeKernel((void*)k_mega, dim3(256), dim3(1024), args, 0, stream);
}

// Round 12
// 269.974 us; speedup vs baseline: 2.2989x; 2.2989x over previous
//
#include <hip/hip_runtime.h>
#include <hip/hip_bf16.h>

#define OUT1 16777216    // 4*64*256*256
#define BIG  33554432    // 4*128*256*256

typedef _Float16 half8 __attribute__((ext_vector_type(8)));
typedef float    floatx4 __attribute__((ext_vector_type(4)));

struct __align__(8) h4s { _Float16 x, y, z, w; };
struct __align__(16) au16 { h4s a, u; };         // 4 px of (a, u) interleaved, one 16-B unit

// ---------------- K0: fold weights (f16): Wch(384x64), biases, -exp(A), Wof(64x128), bct ------
__global__ __launch_bounds__(256) void k_comb(const float* __restrict__ W_in, const float* __restrict__ b_in,
        const float* __restrict__ W_delta, const float* __restrict__ b_delta,
        const float* __restrict__ W_B, const float* __restrict__ b_B,
        const float* __restrict__ A_param, const float* __restrict__ W_out,
        _Float16* __restrict__ Wch, float* __restrict__ bcv, float* __restrict__ negA,
        _Float16* __restrict__ Wof, float* __restrict__ bct){
    int i = blockIdx.x*256 + threadIdx.x;
    if (i < 24576){
        int r = i >> 6, c = i & 63;
        float v;
        if (r < 128) v = W_in[i];
        else if (r < 256){
            int rr = r-128; float s = 0.f;
            for (int k=0;k<128;k++) s = fmaf(W_delta[(rr<<7)+k], W_in[(k<<6)+c], s);
            v = s;
        } else {
            int rr = r-256; float s = 0.f;
            for (int k=0;k<128;k++) s = fmaf(W_B[(rr<<7)+k], W_in[(k<<6)+c], s);
            v = s;
        }
        Wch[i] = (_Float16)v;
    } else if (i < 24960){
        int r = i - 24576; float v;
        if (r < 128) v = b_in[r];
        else if (r < 256){
            int rr=r-128; float s = b_delta[rr];
            for (int k=0;k<128;k++) s = fmaf(W_delta[(rr<<7)+k], b_in[k], s);
            v = s;
        } else {
            int rr=r-256; float s = b_B[rr];
            for (int k=0;k<128;k++) s = fmaf(W_B[(rr<<7)+k], b_in[k], s);
            v = s;
        }
        bcv[r] = v;
    } else if (i < 25088){
        negA[i-24960] = -expf(A_param[i-24960]);
    } else if (i < 33280){
        Wof[i-25088] = (_Float16)W_out[i-25088];   // [o][k] row-major, 64x128
    } else if (i < 33792){
        // interleaved per-channel epilogue table: bct[c] = (bI, bD, bB, -exp(A))  [float4]
        int j = i - 33280;                         // 0..511
        int c = j >> 2, comp = j & 3;
        float v;
        if (comp == 0) v = b_in[c];
        else if (comp == 1){
            float s = b_delta[c];
            for (int k=0;k<128;k++) s = fmaf(W_delta[(c<<7)+k], b_in[k], s);
            v = s;
        } else if (comp == 2){
            float s = b_B[c];
            for (int k=0;k<128;k++) s = fmaf(W_B[(c<<7)+k], b_in[k], s);
            v = s;
        } else {
            v = -expf(A_param[c]);
        }
        bct[j] = v;
    }
}

// ---------------- K2: MFMA projection v8 — inline bilinear prior (k_prior fused away) --------
__global__ __launch_bounds__(512, 4) void k_proj_mfma(const float* __restrict__ x, const float* __restrict__ prior,
        const _Float16* __restrict__ Wch, const float* __restrict__ bct,
        const float* __restrict__ lam_p, const float* __restrict__ alp_p,
        float* __restrict__ pu, au16* __restrict__ AU){
    __shared__ _Float16 Ws[24576];                 // 384 rows x 64 f16 = 48 KB, swizzled

    const int t    = threadIdx.x;                  // 0..511
    const int lane = t & 63;
    const int wave = t >> 6;                       // 0..7
    const int col  = lane & 15;
    const int quad = lane >> 4;

    const int bl      = blockIdx.x;                // 0..511
    const int b       = bl >> 7;
    const int px_base = (bl & 127) << 9;           // 512-px span per block

    // ---- stage Wch (384x64 f16 = 48 KB) into LDS, XOR-swizzled 16B granules ----
    {
        const float4* wsrc = (const float4*)Wch;   // 3072 x 16B chunks (8 per row)
        #pragma unroll
        for (int i = 0; i < 6; i++){
            int c = t + (i << 9);                  // 0..3071
            int row = c >> 3, part = c & 7;
            float4 v = wsrc[c];
            int byteoff = ((row << 7) + (part << 4)) ^ ((row & 7) << 4);
            *(float4*)((char*)Ws + byteoff) = v;
        }
    }

    const float lamv = lam_p[0], alpv = alp_p[0];
    const float* xcol = x + ((size_t)b<<22) + col; // + k*65536 + px

    // ---- prefetch chunk 0 A-values (f32) ----
    float xf0[8], xf1[8];
    {
        const float* xp = xcol + px_base + (wave<<4);
        #pragma unroll
        for (int j = 0; j < 8; j++){
            xf0[j] = xp[(size_t)(quad*8 + j) << 16];
            xf1[j] = xp[(size_t)(quad*8 + j + 32) << 16];
        }
    }

    __syncthreads();

    const int qb = quad << 4;                      // k-slot byte offset within row
    const char* wsb = (const char*)Ws;

    #pragma unroll 1
    for (int ch = 0; ch < 4; ch++){
        const int pxw = px_base + (ch << 7) + (wave << 4);

        // convert current chunk's A-fragments f32 -> f16
        half8 aX0, aX1;
        #pragma unroll
        for (int j = 0; j < 8; j++){
            aX0[j] = (_Float16)xf0[j];
            aX1[j] = (_Float16)xf1[j];
        }

        // prefetch next chunk (overlaps with this chunk's ct-loop)
        if (ch < 3){
            const float* xn = xcol + pxw + 128;
            #pragma unroll
            for (int j = 0; j < 8; j++){
                xf0[j] = xn[(size_t)(quad*8 + j) << 16];
                xf1[j] = xn[(size_t)(quad*8 + j + 32) << 16];
            }
        }

        // ---- inline bilinear prior (bit-identical to old k_prior) for this lane's 4 px ----
        const float scale = 63.0f/255.0f;
        int yy = pxw >> 8;                         // h-row, constant over the wave tile
        float sy = yy*scale;
        int y0 = min((int)floorf(sy), 63);
        int y1 = min(y0+1, 63);
        float wy = sy - (float)y0;
        const float* pb0 = prior + (b<<12) + (y0<<6);
        const float* pb1 = prior + (b<<12) + (y1<<6);
        int xx0 = (pxw & 255) + (quad<<2);
        float lpu[4], apu[4];
        float4 puo;
        #pragma unroll
        for (int r = 0; r < 4; r++){
            float sx = (float)(xx0 + r)*scale;
            int x0 = min((int)floorf(sx), 63);
            int x1 = min(x0+1, 63);
            float wx = sx - (float)x0;
            float r0 = pb0[x0]*(1.f-wy) + pb1[x0]*wy;
            float r1 = pb0[x1]*(1.f-wy) + pb1[x1]*wy;
            float pv = fminf(fmaxf(r0*(1.f-wx) + r1*wx, -1.f), 1.f);
            ((float*)&puo)[r] = pv;
            lpu[r] = lamv * pv;
            apu[r] = fmaf(alpv, pv, 1.f);
        }
        *(float4*)(pu + (b<<16) + pxw + (quad<<2)) = puo;

        #pragma unroll 2
        for (int ct = 0; ct < 8; ct++){
            int rI = (ct << 4) + col;              // I-group row
            int xr = (rI & 7) << 4;                // XOR term (same for I/D/B rows)
            half8 wI0 = *(const half8*)(wsb + ((( rI       << 7) +      qb) ^ xr));
            half8 wI1 = *(const half8*)(wsb + ((( rI       << 7) + 64 + qb) ^ xr));
            half8 wD0 = *(const half8*)(wsb + ((((rI + 128)<< 7) +      qb) ^ xr));
            half8 wD1 = *(const half8*)(wsb + ((((rI + 128)<< 7) + 64 + qb) ^ xr));
            half8 wB0 = *(const half8*)(wsb + ((((rI + 256)<< 7) +      qb) ^ xr));
            half8 wB1 = *(const half8*)(wsb + ((((rI + 256)<< 7) + 64 + qb) ^ xr));

            floatx4 aI = (floatx4){0.f,0.f,0.f,0.f};
            floatx4 aD = (floatx4){0.f,0.f,0.f,0.f};
            floatx4 aB = (floatx4){0.f,0.f,0.f,0.f};
            aI = __builtin_amdgcn_mfma_f32_16x16x32_f16(aX0, wI0, aI, 0, 0, 0);
            aD = __builtin_amdgcn_mfma_f32_16x16x32_f16(aX0, wD0, aD, 0, 0, 0);
            aB = __builtin_amdgcn_mfma_f32_16x16x32_f16(aX0, wB0, aB, 0, 0, 0);
            aI = __builtin_amdgcn_mfma_f32_16x16x32_f16(aX1, wI1, aI, 0, 0, 0);
            aD = __builtin_amdgcn_mfma_f32_16x16x32_f16(aX1, wD1, aD, 0, 0, 0);
            aB = __builtin_amdgcn_mfma_f32_16x16x32_f16(aX1, wB1, aB, 0, 0, 0);

            // epilogue: lane owns 4 consecutive px of channel ct*16+col
            int c = (ct<<4) + col;                 // channel 0..127
            float4 bv = *(const float4*)(bct + (c<<2));  // (bI, bD, bB, -expA)
            au16 ov;
            #pragma unroll
            for (int r = 0; r < 4; r++){
                float sI = aI[r] + bv.x;
                float sD = aD[r] + bv.y;
                float sB = aB[r] + bv.z;
                float dpre  = sD + lpu[r];
                float delta = fmaxf(dpre, 0.f) + __logf(1.f + __expf(-fabsf(dpre)));
                float ab    = __expf(bv.w * delta);
                float uu    = delta * sB * apu[r] * sI;
                (&ov.a.x)[r] = (_Float16)ab;
                (&ov.u.x)[r] = (_Float16)uu;
            }
            size_t u = (((size_t)((b<<7) + c)) << 14) + (pxw >> 2) + quad;
            AU[u] = ov;
        }
    }
}

// ---------------- K34: fused W+H scan v5b — 1024 threads, 16 waves, 100% occupancy -----------
// One block per (b,c) plane, 1024 threads = 16 waves. Per group of 16 h-rows: wave v W-scans
// row v (one row per wave — 16 rows in parallel), parks raw f16 a/u + f32 Wscan in LDS; one
// barrier; threads 0-255 run the 16-step serial H-recurrence; one barrier; each wave vector-
// stores its row. 512 blocks x 1024 thr = 2 blocks/CU x 16 waves = 32 waves/CU.
// LDS 40 KB. Raw s_barrier keeps the next-group AU prefetch in flight. Column phase order
// identical (v ascending = h ascending) -> bit-identical Sh.
__global__ __launch_bounds__(1024) void k_scan_wh(const au16* __restrict__ AU, _Float16* __restrict__ Sh){
    __shared__ _Float16 As2[16][256], Us2[16][256];  // raw f16 a,u: 8 KB each
    __shared__ float    Wsc[16][256];                // 16 KB
    __shared__ _Float16 Shs[16][256];                // 8 KB   (total 40 KB)

    const int t    = threadIdx.x;                  // 0..1023
    const int lane = t & 63;
    const int wave = t >> 6;                       // 0..15 = row within group
    const size_t plane = (size_t)blockIdx.x;       // b*128 + c
    const size_t bI = plane >> 7, cI = plane & 127;

    float Hcol = 0.f;                              // column state, thread t owns column t (t<256)

    const size_t ub = (plane << 14) + lane;        // au16 units; row r at ub + (r<<6)

    au16 cur = AU[ub + ((size_t)wave << 6)];       // group 0, row = wave

    #pragma unroll 1
    for (int g = 0; g < 16; g++){
        // prefetch next group (stays in flight across the raw barriers)
        au16 nxt = cur;
        if (g < 15) nxt = AU[ub + ((size_t)(((g + 1) << 4) + wave) << 6)];

        // ---- wave W-scan of row (g*16 + wave) ----
        {
            float ax=(float)cur.a.x, ay=(float)cur.a.y, az=(float)cur.a.z, aw=(float)cur.a.w;
            float ux=(float)cur.u.x, uy=(float)cur.u.y, uz=(float)cur.u.z, uw=(float)cur.u.w;

            float A = ax, U = ux;
            U = fmaf(ay, U, uy); A *= ay;
            U = fmaf(az, U, uz); A *= az;
            U = fmaf(aw, U, uw); A *= aw;
            #pragma unroll
            for (int off=1; off<64; off<<=1){
                float Apv = __shfl_up(A, off, 64);
                float Upv = __shfl_up(U, off, 64);
                if (lane >= off){ U = fmaf(A, Upv, U); A *= Apv; }
            }
            float h = __shfl_up(U, 1, 64);         // exclusive prefix
            if (lane == 0) h = 0.f;
            float4 o;
            h = fmaf(ax, h, ux); o.x = h;
            h = fmaf(ay, h, uy); o.y = h;
            h = fmaf(az, h, uz); o.z = h;
            h = fmaf(aw, h, uw); o.w = h;

            int c0 = lane << 2;
            *(h4s*)&As2[wave][c0] = cur.a;         // raw f16 (bit-exact park)
            *(h4s*)&Us2[wave][c0] = cur.u;
            *(float4*)&Wsc[wave][c0] = o;
        }

        asm volatile("s_waitcnt lgkmcnt(0)" ::: "memory");
        __builtin_amdgcn_sched_barrier(0);
        __builtin_amdgcn_s_barrier();              // raw: AU prefetch stays in flight
        __builtin_amdgcn_sched_barrier(0);

        // ---- column phase: serial H-recurrence over 16 rows (identical order) ----
        if (t < 256){
            #pragma unroll
            for (int v = 0; v < 16; v++){
                Hcol = fmaf((float)As2[v][t], Hcol, (float)Us2[v][t]);
                Shs[v][t] = (_Float16)(Hcol + Wsc[v][t]);
            }
        }

        asm volatile("s_waitcnt lgkmcnt(0)" ::: "memory");
        __builtin_amdgcn_sched_barrier(0);
        __builtin_amdgcn_s_barrier();
        __builtin_amdgcn_sched_barrier(0);

        // ---- vector store: wave v writes row h=g*16+v, [b][h][c][w] layout ----
        {
            h4s sv = *(h4s*)&Shs[wave][lane << 2];
            size_t hh = (size_t)((g << 4) + wave);
            *(h4s*)(Sh + (bI<<23) + (hh<<15) + (cI<<8) + (lane<<2)) = sv;
        }

        cur = nxt;
    }
}

// ---------------- K5: MFMA output conv (128->64) + residual — Sh [b][h][c][w] tile-local ------
__global__ __launch_bounds__(256, 4) void k_out_mfma(const float* __restrict__ x, const _Float16* __restrict__ Sh,
        const _Float16* __restrict__ Wof, const float* __restrict__ bout, const float* __restrict__ gam_p,
        float* __restrict__ out){
    const int t    = threadIdx.x;
    const int lane = t & 63;
    const int wave = t >> 6;
    const int col  = lane & 15;
    const int quad = lane >> 4;
    const int b    = blockIdx.x >> 8;
    const int hh   = blockIdx.x & 255;         // h-row
    const int p0   = hh << 8;
    const int wn0  = wave << 6;                // this wave's 64 px (w-range)

    const _Float16* shb = Sh + ((size_t)b<<23) + ((size_t)hh<<15);   // [c][w] 64KB tile

    floatx4 acc[4][4];                         // [mt=px-tile][nt=out-ch-tile]
    #pragma unroll
    for (int mt = 0; mt < 4; mt++)
        #pragma unroll
        for (int nt = 0; nt < 4; nt++)
            acc[mt][nt] = (floatx4){0.f,0.f,0.f,0.f};

    #pragma unroll
    for (int kc = 0; kc < 4; kc++){
        half8 af[4];                           // Sh[c = kc*32+quad*8+j][w = wn0+mt*16+col]
        #pragma unroll
        for (int mt = 0; mt < 4; mt++)
            #pragma unroll
            for (int j = 0; j < 8; j++)
                af[mt][j] = shb[((kc*32 + quad*8 + j)<<8) + wn0 + mt*16 + col];
        half8 bf[4];                           // Wof[n = nt*16+col][k]  (16B vector loads)
        #pragma unroll
        for (int nt = 0; nt < 4; nt++)
            bf[nt] = *(const half8*)(Wof + (nt*16 + col)*128 + kc*32 + quad*8);
        #pragma unroll
        for (int mt = 0; mt < 4; mt++)
            #pragma unroll
            for (int nt = 0; nt < 4; nt++)
                acc[mt][nt] = __builtin_amdgcn_mfma_f32_16x16x32_f16(af[mt], bf[nt], acc[mt][nt], 0, 0, 0);
    }

    const float gv = gam_p[0];
    #pragma unroll
    for (int nt = 0; nt < 4; nt++){
        int o = nt*16 + col;                   // out channel 0..63
        float bo = bout[o];
        #pragma unroll
        for (int mt = 0; mt < 4; mt++){
            size_t idx = (((size_t)(b*64 + o))<<16) + p0 + wn0 + mt*16 + (quad<<2);
            float4 xv = *(const float4*)(x + idx);
            float4 ov;
            ov.x = fmaf(gv, acc[mt][nt][0] + bo, xv.x);
            ov.y = fmaf(gv, acc[mt][nt][1] + bo, xv.y);
            ov.z = fmaf(gv, acc[mt][nt][2] + bo, xv.z);
            ov.w = fmaf(gv, acc[mt][nt][3] + bo, xv.w);
            *(float4*)(out + idx) = ov;
        }
    }
}

extern "C" void kernel_launch(void* const* d_in, const int* in_sizes, int n_in,
                              void* d_out, int out_size, void* d_ws, size_t ws_size,
                              hipStream_t stream){
    const float* x       = (const float*)d_in[0];
    const float* prior   = (const float*)d_in[1];
    const float* W_in    = (const float*)d_in[2];
    const float* b_in    = (const float*)d_in[3];
    const float* W_out   = (const float*)d_in[4];
    const float* b_out   = (const float*)d_in[5];
    const float* W_delta = (const float*)d_in[6];
    const float* b_delta = (const float*)d_in[7];
    const float* W_B     = (const float*)d_in[8];
    const float* b_B     = (const float*)d_in[9];
    const float* A_param = (const float*)d_in[10];
    const float* lam     = (const float*)d_in[11];
    const float* alp     = (const float*)d_in[12];
    const float* gam     = (const float*)d_in[13];

    float* out = (float*)d_out;
    float* pu  = out + OUT1;                   // prior_up = output 1

    float* ws        = (float*)d_ws;
    _Float16* Wch    = (_Float16*)ws;          // 24576 f16 -> float-offset [0,12288)
    float* bcv       = ws + 12288;             // 384
    float* negA      = ws + 12672;             // 128
    _Float16* Wof    = (_Float16*)(ws + 12800);// 8192 f16 -> [12800,16896)
    float* bct       = ws + 16896;             // 512 floats (128 x float4)
    au16* AU         = (au16*)(ws + 32768);    // BIG/4 units x 16 B = 134 MB
    _Float16* Sh     = (_Float16*)(AU + BIG/4);// BIG f16 = 67 MB, layout [b][h][c][w]

    hipLaunchKernelGGL(k_comb,   dim3(132),   dim3(256), 0, stream, W_in, b_in, W_delta, b_delta,
                       W_B, b_B, A_param, W_out, Wch, bcv, negA, Wof, bct);
    hipLaunchKernelGGL(k_proj_mfma, dim3(512), dim3(512), 0, stream,
                       x, prior, Wch, bct, lam, alp, pu, AU);
    hipLaunchKernelGGL(k_scan_wh, dim3(512), dim3(1024), 0, stream, AU, Sh);
    hipLaunchKernelGGL(k_out_mfma, dim3(1024), dim3(256), 0, stream, x, Sh, Wof, b_out, gam, out);
}